// Round 1
// baseline (113.096 us; speedup 1.0000x reference)
//
#include <hip/hip_runtime.h>
#include <hip/hip_bf16.h>
#include <stdint.h>

#define NROWS 8192
#define BROWS 4096
#define D 256
#define SCALE_E2 14.426950408889634f  // (1/T)*log2(e), T=0.1

#define M_TILE 128
#define NT 64
#define CSPLIT 8
#define COLS_PER (NROWS / CSPLIT)   // 1024
#define NTILES (COLS_PER / NT)      // 16

typedef __attribute__((ext_vector_type(8))) short bf16x8;
typedef __attribute__((ext_vector_type(4))) float f32x4;

__device__ inline void gload_lds16(const void* g, void* l) {
  __builtin_amdgcn_global_load_lds((const __attribute__((address_space(1))) void*)g,
                                   (__attribute__((address_space(3))) void*)l,
                                   16, 0, 0);
}

__device__ inline unsigned short f2bf(float x) {
  __hip_bfloat16 h = __float2bfloat16(x);
  return __builtin_bit_cast(unsigned short, h);
}

// Kernel A: L2-normalize rows -> bf16 reps; store inv-norm; zero denom and out.
__global__ __launch_bounds__(256) void knorm(const float* __restrict__ zi,
                                             const float* __restrict__ zj,
                                             unsigned short* __restrict__ reps,
                                             float* __restrict__ invn,
                                             float* __restrict__ denom,
                                             float* __restrict__ out) {
  int w = threadIdx.x >> 6, l = threadIdx.x & 63;
  int row = blockIdx.x * 4 + w;
  const float* src = (row < BROWS) ? (zi + (size_t)row * D)
                                   : (zj + (size_t)(row - BROWS) * D);
  float4 v = ((const float4*)src)[l];
  float ss = v.x * v.x + v.y * v.y + v.z * v.z + v.w * v.w;
#pragma unroll
  for (int m = 1; m < 64; m <<= 1) ss += __shfl_xor(ss, m, 64);
  float n = sqrtf(ss);
  float sc = 1.0f / fmaxf(n, 1e-12f);
  ushort4 o;
  o.x = f2bf(v.x * sc); o.y = f2bf(v.y * sc);
  o.z = f2bf(v.z * sc); o.w = f2bf(v.w * sc);
  ((ushort4*)reps)[(size_t)row * 64 + l] = o;
  if (l == 0) { invn[row] = sc; denom[row] = 0.f; }
  if (row == 0 && l == 0) out[0] = 0.f;
}

// Kernel P: positive-pair dots in fp32; adds -(1/N)*sum_i pos_i/T to out.
__global__ __launch_bounds__(256) void kpos(const float* __restrict__ zi,
                                            const float* __restrict__ zj,
                                            const float* __restrict__ invn,
                                            float* __restrict__ out) {
  int w = threadIdx.x >> 6, l = threadIdx.x & 63;
  int p = blockIdx.x * 4 + w;
  float4 a = ((const float4*)(zi + (size_t)p * D))[l];
  float4 b = ((const float4*)(zj + (size_t)p * D))[l];
  float d = a.x * b.x + a.y * b.y + a.z * b.z + a.w * b.w;
#pragma unroll
  for (int m = 1; m < 64; m <<= 1) d += __shfl_xor(d, m, 64);
  if (l == 0) {
    // loss contribution: -(2/(N*T)) * cos_p ; N=8192, T=0.1
    atomicAdd(out, d * invn[p] * invn[p + BROWS] * (-2.0f / (8192.0f * 0.1f)));
  }
}

// Kernel B: fused sim-tile MFMA + exp + row-sum accumulate into denom[].
__global__ __launch_bounds__(256, 2) void ksim(const unsigned short* __restrict__ reps_,
                                               float* __restrict__ denom) {
  __shared__ uint4 smem[2][2048];  // 2 x 64 rows x 512B = 64 KB
  const uint4* reps4 = (const uint4*)reps_;
  int tid = threadIdx.x;
  int w = tid >> 6, l = tid & 63;
  int wr = w >> 1, wc = w & 1;          // wave = 64 rows x 32 cols of 128x64 tile
  int rowbase = blockIdx.x * M_TILE;
  int colbase0 = blockIdx.y * COLS_PER;

  // ---- A fragments in registers: lane l holds row (base+fr*16+(l&15)),
  //      k = kk*32 + (l>>4)*8 .. +8  (16B per frag) ----
  bf16x8 a[4][8];
  int arow = rowbase + wr * 64 + (l & 15);
  int kgrp = (l >> 4);
#pragma unroll
  for (int fr = 0; fr < 4; ++fr) {
    const uint4* base = reps4 + (size_t)(arow + fr * 16) * 32 + kgrp;
#pragma unroll
    for (int kk = 0; kk < 8; ++kk) {
      uint4 t = base[kk * 4];
      a[fr][kk] = __builtin_bit_cast(bf16x8, t);
    }
  }

  f32x4 acc[4][2];
  float rowsum[4][4];
#pragma unroll
  for (int fr = 0; fr < 4; ++fr) {
#pragma unroll
    for (int r = 0; r < 4; ++r) rowsum[fr][r] = 0.f;
#pragma unroll
    for (int fc = 0; fc < 2; ++fc)
#pragma unroll
      for (int r = 0; r < 4; ++r) acc[fr][fc][r] = 0.f;
  }

  // ---- staging: 64 rows x 512B per buffer; linear LDS dest, pre-swizzled
  //      global source so reads can XOR-swizzle (involution both sides) ----
  auto stage = [&](int buf, int colbase) {
#pragma unroll
    for (int i = 0; i < 8; ++i) {
      int c = w + 4 * i;                 // 32 chunks of 1KB (2 rows each)
      int lr = 2 * c + (l >> 5);         // local row 0..63
      int gr = colbase + lr;             // global R-row (tile col)
      int kb = ((l & 31) * 16) ^ ((lr & 7) << 4);
      gload_lds16((const char*)reps_ + (size_t)gr * 512 + kb,
                  (void*)&smem[buf][c * 64]);
    }
  };

  stage(0, colbase0);
  __syncthreads();
  int buf = 0;
  for (int t = 0; t < NTILES; ++t) {
    if (t + 1 < NTILES) stage(buf ^ 1, colbase0 + (t + 1) * NT);
    // ---- MFMA over K=256 (8 steps of 32) ----
#pragma unroll
    for (int kk = 0; kk < 8; ++kk) {
      int kb = kk * 64 + (l >> 4) * 16;
      int lr0 = wc * 32 + (l & 15);
      int lr1 = lr0 + 16;
      bf16x8 b0 = *(const bf16x8*)&smem[buf][lr0 * 32 + ((kb ^ ((lr0 & 7) << 4)) >> 4)];
      bf16x8 b1 = *(const bf16x8*)&smem[buf][lr1 * 32 + ((kb ^ ((lr1 & 7) << 4)) >> 4)];
#pragma unroll
      for (int fr = 0; fr < 4; ++fr) {
        acc[fr][0] = __builtin_amdgcn_mfma_f32_16x16x32_bf16(a[fr][kk], b0, acc[fr][0], 0, 0, 0);
        acc[fr][1] = __builtin_amdgcn_mfma_f32_16x16x32_bf16(a[fr][kk], b1, acc[fr][1], 0, 0, 0);
      }
    }
    // ---- exp + row-sum, diag masked; reset acc ----
    int colt = colbase0 + t * NT;
    int rbase = rowbase + wr * 64 + (l >> 4) * 4;
#pragma unroll
    for (int fr = 0; fr < 4; ++fr) {
#pragma unroll
      for (int fc = 0; fc < 2; ++fc) {
        int cg = colt + wc * 32 + fc * 16 + (l & 15);
#pragma unroll
        for (int r = 0; r < 4; ++r) {
          int rg = rbase + fr * 16 + r;
          float s = acc[fr][fc][r];
          float e = exp2f(s * SCALE_E2);
          e = (rg == cg) ? 0.f : e;
          rowsum[fr][r] += e;
          acc[fr][fc][r] = 0.f;
        }
      }
    }
    __syncthreads();
    buf ^= 1;
  }

  // ---- reduce across the 16 lanes sharing each row; one atomic per row ----
#pragma unroll
  for (int fr = 0; fr < 4; ++fr) {
#pragma unroll
    for (int r = 0; r < 4; ++r) {
      float v = rowsum[fr][r];
      v += __shfl_xor(v, 1, 64);
      v += __shfl_xor(v, 2, 64);
      v += __shfl_xor(v, 4, 64);
      v += __shfl_xor(v, 8, 64);
      if ((l & 15) == 0)
        atomicAdd(&denom[rowbase + wr * 64 + fr * 16 + (l >> 4) * 4 + r], v);
    }
  }
}

// Kernel F: + (1/N) * sum_i log(denom_i)
__global__ __launch_bounds__(256) void kfin(const float* __restrict__ denom,
                                            float* __restrict__ out) {
  int i = blockIdx.x * 256 + threadIdx.x;
  float v = logf(denom[i]) * (1.0f / 8192.0f);
#pragma unroll
  for (int m = 1; m < 64; m <<= 1) v += __shfl_xor(v, m, 64);
  __shared__ float part[4];
  if ((threadIdx.x & 63) == 0) part[threadIdx.x >> 6] = v;
  __syncthreads();
  if (threadIdx.x == 0)
    atomicAdd(out, part[0] + part[1] + part[2] + part[3]);
}

extern "C" void kernel_launch(void* const* d_in, const int* in_sizes, int n_in,
                              void* d_out, int out_size, void* d_ws, size_t ws_size,
                              hipStream_t stream) {
  (void)in_sizes; (void)n_in; (void)out_size; (void)ws_size;
  const float* zi = (const float*)d_in[0];
  const float* zj = (const float*)d_in[1];
  float* out = (float*)d_out;
  char* ws = (char*)d_ws;
  unsigned short* reps = (unsigned short*)ws;                 // 8192*256*2 = 4 MB
  float* invn = (float*)(ws + 4194304);                       // 32 KB
  float* denom = (float*)(ws + 4194304 + 32768);              // 32 KB

  knorm<<<2048, 256, 0, stream>>>(zi, zj, reps, invn, denom, out);
  kpos<<<1024, 256, 0, stream>>>(zi, zj, invn, out);
  ksim<<<dim3(64, 8), 256, 0, stream>>>(reps, denom);
  kfin<<<32, 256, 0, stream>>>(denom, out);
}

// Round 2
// 76.526 us; speedup vs baseline: 1.4779x; 1.4779x over previous
//
#include <hip/hip_runtime.h>
#include <hip/hip_bf16.h>
#include <stdint.h>

#define NROWS 8192
#define BROWS 4096
#define D 256
#define SCALE_E2 14.426950408889634f  // (1/T)*log2(e), T=0.1

#define M_TILE 128
#define NT 64
#define CSPLIT 8
#define COLS_PER (NROWS / CSPLIT)   // 1024
#define NTILES (COLS_PER / NT)      // 16

typedef __attribute__((ext_vector_type(8))) short bf16x8;
typedef __attribute__((ext_vector_type(4))) float f32x4;

__device__ inline void gload_lds16(const void* g, void* l) {
  __builtin_amdgcn_global_load_lds((const __attribute__((address_space(1))) void*)g,
                                   (__attribute__((address_space(3))) void*)l,
                                   16, 0, 0);
}

__device__ inline unsigned short f2bf(float x) {
  __hip_bfloat16 h = __float2bfloat16(x);
  return __builtin_bit_cast(unsigned short, h);
}

// Kernel A: L2-normalize rows -> bf16 reps; zero denom and out.
__global__ __launch_bounds__(256) void knorm(const float* __restrict__ zi,
                                             const float* __restrict__ zj,
                                             unsigned short* __restrict__ reps,
                                             float* __restrict__ denom,
                                             float* __restrict__ out) {
  int w = threadIdx.x >> 6, l = threadIdx.x & 63;
  int row = blockIdx.x * 4 + w;
  const float* src = (row < BROWS) ? (zi + (size_t)row * D)
                                   : (zj + (size_t)(row - BROWS) * D);
  float4 v = ((const float4*)src)[l];
  float ss = v.x * v.x + v.y * v.y + v.z * v.z + v.w * v.w;
#pragma unroll
  for (int m = 1; m < 64; m <<= 1) ss += __shfl_xor(ss, m, 64);
  float n = sqrtf(ss);
  float sc = 1.0f / fmaxf(n, 1e-12f);
  ushort4 o;
  o.x = f2bf(v.x * sc); o.y = f2bf(v.y * sc);
  o.z = f2bf(v.z * sc); o.w = f2bf(v.w * sc);
  ((ushort4*)reps)[(size_t)row * 64 + l] = o;
  if (l == 0) denom[row] = 0.f;
  if (row == 0 && l == 0) out[0] = 0.f;
}

// Kernel B: fused sim-tile MFMA + exp + row-sum accumulate into denom[];
// also captures the positive-pair similarity pos[row] = sim[row, row±B].
__global__ __launch_bounds__(256, 2) void ksim(const unsigned short* __restrict__ reps_,
                                               float* __restrict__ denom,
                                               float* __restrict__ pos) {
  __shared__ uint4 smem[2][2048];  // 2 x 64 rows x 512B = 64 KB
  const uint4* reps4 = (const uint4*)reps_;
  int tid = threadIdx.x;
  int w = tid >> 6, l = tid & 63;
  int wr = w >> 1, wc = w & 1;          // wave = 64 rows x 32 cols of 128x64 tile
  int rowbase = blockIdx.x * M_TILE;
  int colbase0 = blockIdx.y * COLS_PER;

  // ---- A fragments in registers: lane l holds row (base+fr*16+(l&15)),
  //      k = kk*32 + (l>>4)*8 .. +8  (16B per frag) ----
  bf16x8 a[4][8];
  int arow = rowbase + wr * 64 + (l & 15);
  int kgrp = (l >> 4);
#pragma unroll
  for (int fr = 0; fr < 4; ++fr) {
    const uint4* base = reps4 + (size_t)(arow + fr * 16) * 32 + kgrp;
#pragma unroll
    for (int kk = 0; kk < 8; ++kk) {
      uint4 t = base[kk * 4];
      a[fr][kk] = __builtin_bit_cast(bf16x8, t);
    }
  }

  f32x4 acc[4][2];
  float rowsum[4][4];
#pragma unroll
  for (int fr = 0; fr < 4; ++fr) {
#pragma unroll
    for (int r = 0; r < 4; ++r) rowsum[fr][r] = 0.f;
#pragma unroll
    for (int fc = 0; fc < 2; ++fc)
#pragma unroll
      for (int r = 0; r < 4; ++r) acc[fr][fc][r] = 0.f;
  }

  // ---- staging: 64 rows x 512B per buffer; linear LDS dest, pre-swizzled
  //      global source so reads can XOR-swizzle (involution both sides) ----
  auto stage = [&](int buf, int colbase) {
#pragma unroll
    for (int i = 0; i < 8; ++i) {
      int c = w + 4 * i;                 // 32 chunks of 1KB (2 rows each)
      int lr = 2 * c + (l >> 5);         // local row 0..63
      int gr = colbase + lr;             // global R-row (tile col)
      int kb = ((l & 31) * 16) ^ ((lr & 7) << 4);
      gload_lds16((const char*)reps_ + (size_t)gr * 512 + kb,
                  (void*)&smem[buf][c * 64]);
    }
  };

  stage(0, colbase0);
  __syncthreads();
  int buf = 0;
  for (int t = 0; t < NTILES; ++t) {
    if (t + 1 < NTILES) stage(buf ^ 1, colbase0 + (t + 1) * NT);
    // ---- MFMA over K=256 (8 steps of 32) ----
#pragma unroll
    for (int kk = 0; kk < 8; ++kk) {
      int kb = kk * 64 + (l >> 4) * 16;
      int lr0 = wc * 32 + (l & 15);
      int lr1 = lr0 + 16;
      bf16x8 b0 = *(const bf16x8*)&smem[buf][lr0 * 32 + ((kb ^ ((lr0 & 7) << 4)) >> 4)];
      bf16x8 b1 = *(const bf16x8*)&smem[buf][lr1 * 32 + ((kb ^ ((lr1 & 7) << 4)) >> 4)];
#pragma unroll
      for (int fr = 0; fr < 4; ++fr) {
        acc[fr][0] = __builtin_amdgcn_mfma_f32_16x16x32_bf16(a[fr][kk], b0, acc[fr][0], 0, 0, 0);
        acc[fr][1] = __builtin_amdgcn_mfma_f32_16x16x32_bf16(a[fr][kk], b1, acc[fr][1], 0, 0, 0);
      }
    }
    // ---- exp + row-sum, diag masked, positive captured; reset acc ----
    int colt = colbase0 + t * NT;
    int rbase = rowbase + wr * 64 + (l >> 4) * 4;
#pragma unroll
    for (int fr = 0; fr < 4; ++fr) {
#pragma unroll
      for (int fc = 0; fc < 2; ++fc) {
        int cg = colt + wc * 32 + fc * 16 + (l & 15);
#pragma unroll
        for (int r = 0; r < 4; ++r) {
          int rg = rbase + fr * 16 + r;
          float s = acc[fr][fc][r];
          float e = exp2f(s * SCALE_E2);
          e = (rg == cg) ? 0.f : e;
          rowsum[fr][r] += e;
          int posc = (rg < BROWS) ? rg + BROWS : rg - BROWS;
          if (cg == posc) pos[rg] = s;   // written exactly once per row
          acc[fr][fc][r] = 0.f;
        }
      }
    }
    __syncthreads();
    buf ^= 1;
  }

  // ---- reduce across the 16 lanes sharing each row; one atomic per row ----
#pragma unroll
  for (int fr = 0; fr < 4; ++fr) {
#pragma unroll
    for (int r = 0; r < 4; ++r) {
      float v = rowsum[fr][r];
      v += __shfl_xor(v, 1, 64);
      v += __shfl_xor(v, 2, 64);
      v += __shfl_xor(v, 4, 64);
      v += __shfl_xor(v, 8, 64);
      if ((l & 15) == 0)
        atomicAdd(&denom[rowbase + wr * 64 + fr * 16 + (l >> 4) * 4 + r], v);
    }
  }
}

// Kernel F: + (1/N) * sum_i (log(denom_i) - pos_i/T)
__global__ __launch_bounds__(256) void kfin(const float* __restrict__ denom,
                                            const float* __restrict__ pos,
                                            float* __restrict__ out) {
  int i = blockIdx.x * 256 + threadIdx.x;
  float v = (logf(denom[i]) - pos[i] * 10.0f) * (1.0f / 8192.0f);
#pragma unroll
  for (int m = 1; m < 64; m <<= 1) v += __shfl_xor(v, m, 64);
  __shared__ float part[4];
  if ((threadIdx.x & 63) == 0) part[threadIdx.x >> 6] = v;
  __syncthreads();
  if (threadIdx.x == 0)
    atomicAdd(out, part[0] + part[1] + part[2] + part[3]);
}

extern "C" void kernel_launch(void* const* d_in, const int* in_sizes, int n_in,
                              void* d_out, int out_size, void* d_ws, size_t ws_size,
                              hipStream_t stream) {
  (void)in_sizes; (void)n_in; (void)out_size; (void)ws_size;
  const float* zi = (const float*)d_in[0];
  const float* zj = (const float*)d_in[1];
  float* out = (float*)d_out;
  char* ws = (char*)d_ws;
  unsigned short* reps = (unsigned short*)ws;                 // 8192*256*2 = 4 MB
  float* denom = (float*)(ws + 4194304);                      // 32 KB
  float* pos   = (float*)(ws + 4194304 + 32768);              // 32 KB

  knorm<<<2048, 256, 0, stream>>>(zi, zj, reps, denom, out);
  ksim<<<dim3(64, 8), 256, 0, stream>>>(reps, denom, pos);
  kfin<<<32, 256, 0, stream>>>(denom, pos, out);
}